// Round 18
// baseline (419.436 us; speedup 1.0000x reference)
//
#include <hip/hip_runtime.h>
#include <hip/hip_fp16.h>
#include <cmath>

#define NLEV 16
#define HASH_START 12               // levels >= 12 use spatial hash ((r+1)^2 > 2^19)
#define HMASK ((1u << 19) - 1u)     // hash level size is exactly 2^19
#define HASH_PRIME 2654435761u
#define LDS_WORDS 14160             // offset[6]: entries of levels 0-5 (host-guarded)

typedef float    f4 __attribute__((ext_vector_type(4)));
typedef unsigned u4 __attribute__((ext_vector_type(4)));

struct LvlC {
  float scale[NLEV];
  unsigned stride[NLEV];   // res + 1
  unsigned offset[NLEV];   // cumulative param offset (multiple of 8)
};

__device__ __forceinline__ float2 h2f(unsigned u) {
  return __half22float2(__builtin_bit_cast(__half2, u));
}

// ---- pass 0: fp32 tables -> fp16 copies in ws ----
__global__ __launch_bounds__(256) void k_convert(
    const float2* __restrict__ t0, const float2* __restrict__ t1,
    const float2* __restrict__ t2, unsigned* __restrict__ dst, unsigned total)
{
  unsigned g = blockIdx.x * 256 + threadIdx.x;
  unsigned stp = gridDim.x * 256;
  unsigned tot3 = 3u * total;
  for (unsigned e = g; e < tot3; e += stp) {
    const float2* src; unsigned i = e;
    if (i < total)            { src = t0; }
    else if (i < 2u * total)  { src = t1; i -= total; }
    else                      { src = t2; i -= 2u * total; }
    float2 v = src[i];
    __half2 h = __floats2half2_rn(v.x, v.y);
    __builtin_nontemporal_store(__builtin_bit_cast(unsigned, h), dst + e);
  }
}

// even-x0 trick: (x0+1)^hy == (x0^hy)^1 when x0 even -> aligned uint2 pair
__device__ __forceinline__ void hash_row(
    const unsigned* __restrict__ tp, unsigned x0, unsigned hy,
    unsigned& g0, unsigned& g1)
{
  unsigned a0 = (x0 ^ hy) & HMASK;
  if ((x0 & 1u) == 0u) {
    uint2 v = *reinterpret_cast<const uint2*>(tp + (a0 & ~1u));
    bool hi = (a0 & 1u) != 0u;
    g0 = hi ? v.y : v.x;
    g1 = hi ? v.x : v.y;
  } else {
    g0 = tp[a0];
    g1 = tp[((x0 + 1u) ^ hy) & HMASK];
  }
}

// ---- issue/consume helpers (forceinline, fully unrolled -> regs) ----
__device__ __forceinline__ void issue_dense(
    const unsigned* __restrict__ tab, size_t total, const LvlC& lc, int l0,
    const float* ua, const float* ub,
    uint2 (&g)[2][3][2], float (&gx)[2][3], float (&gy)[2][3])
{
#pragma unroll
  for (int h = 0; h < 2; ++h) {
    const float sc = lc.scale[l0 + h];
    const unsigned st = lc.stride[l0 + h], o = lc.offset[l0 + h];
#pragma unroll
    for (int q = 0; q < 3; ++q) {
      float px = ua[q] * sc + .5f, py = ub[q] * sc + .5f;
      float fx = floorf(px), fy = floorf(py);
      gx[h][q] = px - fx; gy[h][q] = py - fy;
      unsigned i00 = (unsigned)fx + (unsigned)fy * st + o;
      const unsigned* tp = tab + (size_t)q * total;
      g[h][q][0] = *reinterpret_cast<const uint2*>(tp + i00);
      g[h][q][1] = *reinterpret_cast<const uint2*>(tp + i00 + st);
    }
  }
}

__device__ __forceinline__ void consume_dense(
    const uint2 (&g)[2][3][2], const float (&gx)[2][3], const float (&gy)[2][3],
    float* res4)
{
#pragma unroll
  for (int h = 0; h < 2; ++h) {
    float s0 = 0.f, s1 = 0.f;
#pragma unroll
    for (int q = 0; q < 3; ++q) {
      float x = gx[h][q], y = gy[h][q];
      float w00 = (1.f - x) * (1.f - y), w10 = x * (1.f - y);
      float w01 = (1.f - x) * y,          w11 = x * y;
      float2 f00 = h2f(g[h][q][0].x), f10 = h2f(g[h][q][0].y);
      float2 f01 = h2f(g[h][q][1].x), f11 = h2f(g[h][q][1].y);
      s0 += w00 * f00.x + w10 * f10.x + w01 * f01.x + w11 * f11.x;
      s1 += w00 * f00.y + w10 * f10.y + w01 * f01.y + w11 * f11.y;
    }
    res4[2 * h + 0] = s0; res4[2 * h + 1] = s1;
  }
}

__device__ __forceinline__ void issue_hash2(
    const unsigned* __restrict__ tab, size_t total, const LvlC& lc, int l0,
    const float* ua, const float* ub,
    unsigned (&g)[2][3][4], float (&rx)[2][3], float (&ry)[2][3])
{
#pragma unroll
  for (int h = 0; h < 2; ++h) {
    const float sc = lc.scale[l0 + h];
    const unsigned o = lc.offset[l0 + h];
#pragma unroll
    for (int q = 0; q < 3; ++q) {
      float px = ua[q] * sc + .5f, py = ub[q] * sc + .5f;
      float fx = floorf(px), fy = floorf(py);
      rx[h][q] = px - fx; ry[h][q] = py - fy;
      unsigned x0 = (unsigned)fx, y0 = (unsigned)fy;
      unsigned hy0 = y0 * HASH_PRIME, hy1 = hy0 + HASH_PRIME;
      const unsigned* tp = tab + (size_t)q * total + o;
      hash_row(tp, x0, hy0, g[h][q][0], g[h][q][1]);
      hash_row(tp, x0, hy1, g[h][q][2], g[h][q][3]);
    }
  }
}

__device__ __forceinline__ void consume_hash2(
    const unsigned (&g)[2][3][4], const float (&rx)[2][3], const float (&ry)[2][3],
    float* res4)
{
#pragma unroll
  for (int h = 0; h < 2; ++h) {
    float s0 = 0.f, s1 = 0.f;
#pragma unroll
    for (int q = 0; q < 3; ++q) {
      float x = rx[h][q], y = ry[h][q];
      float w00 = (1.f - x) * (1.f - y), w10 = x * (1.f - y);
      float w01 = (1.f - x) * y,          w11 = x * y;
      float2 f00 = h2f(g[h][q][0]), f10 = h2f(g[h][q][1]);
      float2 f01 = h2f(g[h][q][2]), f11 = h2f(g[h][q][3]);
      s0 += w00 * f00.x + w10 * f10.x + w01 * f01.x + w11 * f11.x;
      s1 += w00 * f00.y + w10 * f10.y + w01 * f01.y + w11 * f11.y;
    }
    res4[2 * h + 0] = s0; res4[2 * h + 1] = s1;
  }
}

// ---- monolith: per phase p {stage plane p + issue dense group p (+hash)} ->
//      barrier drains all -> LDS compute p -> consume. Hash A issued before
//      phase 0 (consumed after phase 0); hash B after that (consumed after
//      phase 1). All gather queues grind while VALU does LDS work. ----
__global__ __launch_bounds__(512) void k_final(
    const float* __restrict__ pts, const unsigned* __restrict__ tab,
    float* __restrict__ out, LvlC lc, unsigned total, int n)
{
  __shared__ unsigned lds[LDS_WORDS];
  int i = blockIdx.x * 512 + threadIdx.x;   // n % 512 == 0 (host-guarded)

  float u0 = (pts[3 * i + 0] + 1.f) * .5f;
  float u1 = (pts[3 * i + 1] + 1.f) * .5f;
  float u2 = (pts[3 * i + 2] + 1.f) * .5f;
  const float ua[3] = {u0, u0, u1}, ub[3] = {u1, u2, u2};

  float res[32];                  // [0,12) lvl0-5 | [12,24) lvl6-11 | [24,32) lvl12-15
#pragma unroll
  for (int j = 0; j < 12; ++j) res[j] = 0.f;

  uint2 gd[2][3][2];  float dx[2][3], dy[2][3];   // dense group state
  unsigned gh[2][3][4]; float hx[2][3], hyv[2][3]; // hash group state

  // hash group A (levels 12,13): issue now, in flight through phase 0
  issue_hash2(tab, total, lc, 12, ua, ub, gh, hx, hyv);

  // ---------------- phase 0 (plane 0; dense levels 6,7) ----------------
  {
    const u4* src = reinterpret_cast<const u4*>(tab);
    for (unsigned e = threadIdx.x; e < LDS_WORDS / 4; e += 512)
      reinterpret_cast<u4*>(lds)[e] = src[e];
    issue_dense(tab, total, lc, 6, ua, ub, gd, dx, dy);
    __syncthreads();
#pragma unroll
    for (int l = 0; l < 6; ++l) {
      const float sc = lc.scale[l];
      const unsigned st = lc.stride[l], o = lc.offset[l];
      float px = ua[0] * sc + .5f, py = ub[0] * sc + .5f;
      float fx = floorf(px), fy = floorf(py);
      float x = px - fx, y = py - fy;
      unsigned i00 = (unsigned)fx + (unsigned)fy * st + o;
      float2 f00 = h2f(lds[i00]),      f10 = h2f(lds[i00 + 1]);
      float2 f01 = h2f(lds[i00 + st]), f11 = h2f(lds[i00 + st + 1]);
      float w00 = (1.f - x) * (1.f - y), w10 = x * (1.f - y);
      float w01 = (1.f - x) * y,          w11 = x * y;
      res[2 * l + 0] += w00 * f00.x + w10 * f10.x + w01 * f01.x + w11 * f11.x;
      res[2 * l + 1] += w00 * f00.y + w10 * f10.y + w01 * f01.y + w11 * f11.y;
    }
    consume_dense(gd, dx, dy, res + 12);
    consume_hash2(gh, hx, hyv, res + 24);          // A complete (barrier drained)
    issue_hash2(tab, total, lc, 14, ua, ub, gh, hx, hyv);  // group B in flight
  }

  // ---------------- phase 1 (plane 1; dense levels 8,9) ----------------
  {
    __syncthreads();
    const u4* src = reinterpret_cast<const u4*>(tab + (size_t)1 * total);
    for (unsigned e = threadIdx.x; e < LDS_WORDS / 4; e += 512)
      reinterpret_cast<u4*>(lds)[e] = src[e];
    issue_dense(tab, total, lc, 8, ua, ub, gd, dx, dy);
    __syncthreads();
#pragma unroll
    for (int l = 0; l < 6; ++l) {
      const float sc = lc.scale[l];
      const unsigned st = lc.stride[l], o = lc.offset[l];
      float px = ua[1] * sc + .5f, py = ub[1] * sc + .5f;
      float fx = floorf(px), fy = floorf(py);
      float x = px - fx, y = py - fy;
      unsigned i00 = (unsigned)fx + (unsigned)fy * st + o;
      float2 f00 = h2f(lds[i00]),      f10 = h2f(lds[i00 + 1]);
      float2 f01 = h2f(lds[i00 + st]), f11 = h2f(lds[i00 + st + 1]);
      float w00 = (1.f - x) * (1.f - y), w10 = x * (1.f - y);
      float w01 = (1.f - x) * y,          w11 = x * y;
      res[2 * l + 0] += w00 * f00.x + w10 * f10.x + w01 * f01.x + w11 * f11.x;
      res[2 * l + 1] += w00 * f00.y + w10 * f10.y + w01 * f01.y + w11 * f11.y;
    }
    consume_dense(gd, dx, dy, res + 16);
    consume_hash2(gh, hx, hyv, res + 28);          // B complete
  }

  // ---------------- phase 2 (plane 2; dense levels 10,11) ----------------
  {
    __syncthreads();
    const u4* src = reinterpret_cast<const u4*>(tab + (size_t)2 * total);
    for (unsigned e = threadIdx.x; e < LDS_WORDS / 4; e += 512)
      reinterpret_cast<u4*>(lds)[e] = src[e];
    issue_dense(tab, total, lc, 10, ua, ub, gd, dx, dy);
    __syncthreads();
#pragma unroll
    for (int l = 0; l < 6; ++l) {
      const float sc = lc.scale[l];
      const unsigned st = lc.stride[l], o = lc.offset[l];
      float px = ua[2] * sc + .5f, py = ub[2] * sc + .5f;
      float fx = floorf(px), fy = floorf(py);
      float x = px - fx, y = py - fy;
      unsigned i00 = (unsigned)fx + (unsigned)fy * st + o;
      float2 f00 = h2f(lds[i00]),      f10 = h2f(lds[i00 + 1]);
      float2 f01 = h2f(lds[i00 + st]), f11 = h2f(lds[i00 + st + 1]);
      float w00 = (1.f - x) * (1.f - y), w10 = x * (1.f - y);
      float w01 = (1.f - x) * y,          w11 = x * y;
      res[2 * l + 0] += w00 * f00.x + w10 * f10.x + w01 * f01.x + w11 * f11.x;
      res[2 * l + 1] += w00 * f00.y + w10 * f10.y + w01 * f01.y + w11 * f11.y;
    }
    consume_dense(gd, dx, dy, res + 20);
  }

  float4* o4 = (float4*)(out + (size_t)i * 32);
#pragma unroll
  for (int j = 0; j < 8; ++j)
    o4[j] = make_float4(res[4 * j], res[4 * j + 1], res[4 * j + 2], res[4 * j + 3]);
}

// ---- fallback: monolithic fp32 (guards failed) ----
__global__ __launch_bounds__(256) void k_fallback(
    const float* __restrict__ pts, const float2* __restrict__ txy,
    const float2* __restrict__ txz, const float2* __restrict__ tyz,
    float* __restrict__ out, LvlC lc, int n)
{
  int i = blockIdx.x * 256 + threadIdx.x;
  if (i >= n) return;
  float u0 = (pts[3 * i + 0] + 1.f) * .5f;
  float u1 = (pts[3 * i + 1] + 1.f) * .5f;
  float u2 = (pts[3 * i + 2] + 1.f) * .5f;
  const float ua[3] = {u0, u0, u1}, ub[3] = {u1, u2, u2};
  const float2* tabs[3] = {txy, txz, tyz};
  float acc[32];
#pragma unroll
  for (int j = 0; j < 32; ++j) acc[j] = 0.f;
#pragma unroll
  for (int l = 0; l < NLEV; ++l) {
    const float sc = lc.scale[l];
    const unsigned o = lc.offset[l], s = lc.stride[l];
#pragma unroll
    for (int p = 0; p < 3; ++p) {
      const float2* t = tabs[p];
      float px = ua[p] * sc + .5f, py = ub[p] * sc + .5f;
      float fx = floorf(px), fy = floorf(py);
      float rx = px - fx, ry = py - fy;
      unsigned x0 = (unsigned)fx, y0 = (unsigned)fy;
      float w00 = (1.f - rx) * (1.f - ry), w10 = rx * (1.f - ry);
      float w01 = (1.f - rx) * ry,          w11 = rx * ry;
      float2 f00, f10, f01, f11;
      if (l >= HASH_START) {
        unsigned hy0 = y0 * HASH_PRIME, hy1 = hy0 + HASH_PRIME;
        f00 = t[o + ((x0 ^ hy0) & HMASK)];
        f10 = t[o + (((x0 + 1u) ^ hy0) & HMASK)];
        f01 = t[o + ((x0 ^ hy1) & HMASK)];
        f11 = t[o + (((x0 + 1u) ^ hy1) & HMASK)];
      } else {
        unsigned i00 = x0 + y0 * s;
        float4 r0 = *reinterpret_cast<const float4*>(t + o + i00);
        float4 r1 = *reinterpret_cast<const float4*>(t + o + i00 + s);
        f00 = make_float2(r0.x, r0.y); f10 = make_float2(r0.z, r0.w);
        f01 = make_float2(r1.x, r1.y); f11 = make_float2(r1.z, r1.w);
      }
      acc[2 * l + 0] += w00 * f00.x + w10 * f10.x + w01 * f01.x + w11 * f11.x;
      acc[2 * l + 1] += w00 * f00.y + w10 * f10.y + w01 * f01.y + w11 * f11.y;
    }
  }
  float4* o4 = (float4*)(out + (size_t)i * 32);
#pragma unroll
  for (int j = 0; j < 8; ++j)
    o4[j] = make_float4(acc[4 * j], acc[4 * j + 1], acc[4 * j + 2], acc[4 * j + 3]);
}

static unsigned compute_levels(LvlC* lc)
{
  // Mirrors Python _level_constants() with identical double-precision ops.
  const double pls = std::pow(2.0, std::log2(2048.0 / 16.0) / 15.0);
  unsigned long long off = 0;
  for (int l = 0; l < NLEV; ++l) {
    double s = 16.0 * std::pow(pls, (double)l) - 1.0;
    lc->scale[l] = (float)s;
    long long r = (long long)std::ceil(s) + 1;
    long long dense = (r + 1) * (r + 1);
    long long sz = dense < (1LL << 19) ? dense : (1LL << 19);
    sz = ((sz + 7) / 8) * 8;
    lc->stride[l] = (unsigned)(r + 1);
    lc->offset[l] = (unsigned)off;
    off += (unsigned long long)sz;
  }
  return (unsigned)off;
}

extern "C" void kernel_launch(void* const* d_in, const int* in_sizes, int n_in,
                              void* d_out, int out_size, void* d_ws, size_t ws_size,
                              hipStream_t stream) {
  const float*  pts = (const float*)d_in[0];
  const float2* txy = (const float2*)d_in[1];
  const float2* txz = (const float2*)d_in[2];
  const float2* tyz = (const float2*)d_in[3];
  float* out = (float*)d_out;
  int n = in_sizes[0] / 3;  // 1048576 points

  LvlC lc;
  unsigned total = compute_levels(&lc);

  size_t need = (size_t)3 * total * 4;

  bool ok = (n % 512 == 0) && (lc.offset[6] == LDS_WORDS) && (ws_size >= need);
  for (int l = HASH_START; l < NLEV; ++l) {
    unsigned sz = ((l + 1 < NLEV) ? lc.offset[l + 1] : total) - lc.offset[l];
    ok = ok && (sz == (1u << 19));
  }

  int block = 256;
  int grid = (n + block - 1) / block;
  if (!ok) {
    k_fallback<<<grid, block, 0, stream>>>(pts, txy, txz, tyz, out, lc, n);
    return;
  }

  unsigned* tab16 = (unsigned*)d_ws;
  k_convert<<<2048, 256, 0, stream>>>(txy, txz, tyz, tab16, total);
  k_final<<<n / 512, 512, 0, stream>>>(pts, tab16, out, lc, total, n);
}

// Round 19
// 373.690 us; speedup vs baseline: 1.1224x; 1.1224x over previous
//
#include <hip/hip_runtime.h>
#include <hip/hip_fp16.h>
#include <cmath>

#define NLEV 16
#define HASH_START 12               // levels >= 12 use spatial hash ((r+1)^2 > 2^19)
#define HMASK ((1u << 19) - 1u)     // hash level size is exactly 2^19
#define HASH_PRIME 2654435761u
#define LDS_WORDS 14160             // offset[6]: entries of levels 0-5 (host-guarded)

typedef float    f4 __attribute__((ext_vector_type(4)));
typedef unsigned u4 __attribute__((ext_vector_type(4)));

struct LvlC {
  float scale[NLEV];
  unsigned stride[NLEV];   // res + 1
  unsigned offset[NLEV];   // cumulative param offset (multiple of 8)
};

__device__ __forceinline__ float2 h2f(unsigned u) {
  return __half22float2(__builtin_bit_cast(__half2, u));
}

// ---- pass 0: fp32 tables -> fp16 copies in ws ----
__global__ __launch_bounds__(256) void k_convert(
    const float2* __restrict__ t0, const float2* __restrict__ t1,
    const float2* __restrict__ t2, unsigned* __restrict__ dst, unsigned total)
{
  unsigned g = blockIdx.x * 256 + threadIdx.x;
  unsigned stp = gridDim.x * 256;
  unsigned tot3 = 3u * total;
  for (unsigned e = g; e < tot3; e += stp) {
    const float2* src; unsigned i = e;
    if (i < total)            { src = t0; }
    else if (i < 2u * total)  { src = t1; i -= total; }
    else                      { src = t2; i -= 2u * total; }
    float2 v = src[i];
    __half2 h = __floats2half2_rn(v.x, v.y);
    __builtin_nontemporal_store(__builtin_bit_cast(unsigned, h), dst + e);
  }
}

// even-x0 trick: (x0+1)^hy == (x0^hy)^1 when x0 even -> aligned uint2 pair
__device__ __forceinline__ void hash_row(
    const unsigned* __restrict__ tp, unsigned x0, unsigned hy,
    unsigned& g0, unsigned& g1)
{
  unsigned a0 = (x0 ^ hy) & HMASK;
  if ((x0 & 1u) == 0u) {
    uint2 v = *reinterpret_cast<const uint2*>(tp + (a0 & ~1u));
    bool hi = (a0 & 1u) != 0u;
    g0 = hi ? v.y : v.x;
    g1 = hi ? v.x : v.y;
  } else {
    g0 = tp[a0];
    g1 = tp[((x0 + 1u) ^ hy) & HMASK];
  }
}

// ---- prefetch groups hold ONLY loaded words; fracs recomputed at consume ----
__device__ __forceinline__ void issue_dense(
    const unsigned* __restrict__ tab, size_t total, const LvlC& lc, int l0,
    const float* ua, const float* ub, uint2 (&g)[2][3][2])
{
#pragma unroll
  for (int h = 0; h < 2; ++h) {
    const float sc = lc.scale[l0 + h];
    const unsigned st = lc.stride[l0 + h], o = lc.offset[l0 + h];
#pragma unroll
    for (int q = 0; q < 3; ++q) {
      float px = ua[q] * sc + .5f, py = ub[q] * sc + .5f;
      unsigned i00 = (unsigned)floorf(px) + (unsigned)floorf(py) * st + o;
      const unsigned* tp = tab + (size_t)q * total;
      g[h][q][0] = *reinterpret_cast<const uint2*>(tp + i00);
      g[h][q][1] = *reinterpret_cast<const uint2*>(tp + i00 + st);
    }
  }
}

__device__ __forceinline__ void consume_dense(
    const LvlC& lc, int l0, const float* ua, const float* ub,
    const uint2 (&g)[2][3][2], float* res4)
{
#pragma unroll
  for (int h = 0; h < 2; ++h) {
    const float sc = lc.scale[l0 + h];
    float s0 = 0.f, s1 = 0.f;
#pragma unroll
    for (int q = 0; q < 3; ++q) {
      float px = ua[q] * sc + .5f, py = ub[q] * sc + .5f;
      float x = px - floorf(px), y = py - floorf(py);
      float w00 = (1.f - x) * (1.f - y), w10 = x * (1.f - y);
      float w01 = (1.f - x) * y,          w11 = x * y;
      float2 f00 = h2f(g[h][q][0].x), f10 = h2f(g[h][q][0].y);
      float2 f01 = h2f(g[h][q][1].x), f11 = h2f(g[h][q][1].y);
      s0 += w00 * f00.x + w10 * f10.x + w01 * f01.x + w11 * f11.x;
      s1 += w00 * f00.y + w10 * f10.y + w01 * f01.y + w11 * f11.y;
    }
    res4[2 * h + 0] = s0; res4[2 * h + 1] = s1;
  }
}

__device__ __forceinline__ void issue_hash1(
    const unsigned* __restrict__ tab, size_t total, const LvlC& lc, int l,
    const float* ua, const float* ub, unsigned (&g)[3][4])
{
  const float sc = lc.scale[l];
  const unsigned o = lc.offset[l];
#pragma unroll
  for (int q = 0; q < 3; ++q) {
    float px = ua[q] * sc + .5f, py = ub[q] * sc + .5f;
    unsigned x0 = (unsigned)floorf(px), y0 = (unsigned)floorf(py);
    unsigned hy0 = y0 * HASH_PRIME, hy1 = hy0 + HASH_PRIME;
    const unsigned* tp = tab + (size_t)q * total + o;
    hash_row(tp, x0, hy0, g[q][0], g[q][1]);
    hash_row(tp, x0, hy1, g[q][2], g[q][3]);
  }
}

__device__ __forceinline__ void consume_hash1(
    const LvlC& lc, int l, const float* ua, const float* ub,
    const unsigned (&g)[3][4], float* res2)
{
  const float sc = lc.scale[l];
  float s0 = 0.f, s1 = 0.f;
#pragma unroll
  for (int q = 0; q < 3; ++q) {
    float px = ua[q] * sc + .5f, py = ub[q] * sc + .5f;
    float x = px - floorf(px), y = py - floorf(py);
    float w00 = (1.f - x) * (1.f - y), w10 = x * (1.f - y);
    float w01 = (1.f - x) * y,          w11 = x * y;
    float2 f00 = h2f(g[q][0]), f10 = h2f(g[q][1]);
    float2 f01 = h2f(g[q][2]), f11 = h2f(g[q][3]);
    s0 += w00 * f00.x + w10 * f10.x + w01 * f01.x + w11 * f11.x;
    s1 += w00 * f00.y + w10 * f10.y + w01 * f01.y + w11 * f11.y;
  }
  res2[0] = s0; res2[1] = s1;
}

// ---- monolith, spill-safe: per phase {stage plane p + issue dense group p +
//      (re)issue 1-level hash} -> barrier drains all queues -> LDS compute ->
//      consume groups. Peak live: res32 + dense24 + hash12 + coords. ----
__global__ __launch_bounds__(512) void k_final(
    const float* __restrict__ pts, const unsigned* __restrict__ tab,
    float* __restrict__ out, LvlC lc, unsigned total, int n)
{
  __shared__ unsigned lds[LDS_WORDS];
  int i = blockIdx.x * 512 + threadIdx.x;   // n % 512 == 0 (host-guarded)

  float u0 = (pts[3 * i + 0] + 1.f) * .5f;
  float u1 = (pts[3 * i + 1] + 1.f) * .5f;
  float u2 = (pts[3 * i + 2] + 1.f) * .5f;
  const float ua[3] = {u0, u0, u1}, ub[3] = {u1, u2, u2};

  float res[32];                  // [0,12) lvl0-5 | [12,24) lvl6-11 | [24,32) lvl12-15
#pragma unroll
  for (int j = 0; j < 12; ++j) res[j] = 0.f;

  uint2 gd[2][3][2];              // dense prefetch (24 regs)
  unsigned gh[3][4];              // hash prefetch (12 regs)

  issue_hash1(tab, total, lc, 12, ua, ub, gh);

#pragma unroll 1
  for (int p = 0; p < 3; ++p) {
    if (p) __syncthreads();
    const u4* src = reinterpret_cast<const u4*>(tab + (size_t)p * total);
    for (unsigned e = threadIdx.x; e < LDS_WORDS / 4; e += 512)
      reinterpret_cast<u4*>(lds)[e] = src[e];
    issue_dense(tab, total, lc, 6 + 2 * p, ua, ub, gd);
    __syncthreads();               // drains staging + dense + hash queues together
#pragma unroll
    for (int l = 0; l < 6; ++l) {
      const float sc = lc.scale[l];
      const unsigned st = lc.stride[l], o = lc.offset[l];
      float px = ua[p] * sc + .5f, py = ub[p] * sc + .5f;
      float fx = floorf(px), fy = floorf(py);
      float x = px - fx, y = py - fy;
      unsigned i00 = (unsigned)fx + (unsigned)fy * st + o;
      float2 f00 = h2f(lds[i00]),      f10 = h2f(lds[i00 + 1]);
      float2 f01 = h2f(lds[i00 + st]), f11 = h2f(lds[i00 + st + 1]);
      float w00 = (1.f - x) * (1.f - y), w10 = x * (1.f - y);
      float w01 = (1.f - x) * y,          w11 = x * y;
      res[2 * l + 0] += w00 * f00.x + w10 * f10.x + w01 * f01.x + w11 * f11.x;
      res[2 * l + 1] += w00 * f00.y + w10 * f10.y + w01 * f01.y + w11 * f11.y;
    }
    consume_dense(lc, 6 + 2 * p, ua, ub, gd, res + 12 + 4 * p);
    consume_hash1(lc, 12 + p, ua, ub, gh, res + 24 + 2 * p);
    if (p < 2) issue_hash1(tab, total, lc, 13 + p, ua, ub, gh);
  }

  // tail hash level 15: issue + immediate consume (latency hidden by TLP)
  issue_hash1(tab, total, lc, 15, ua, ub, gh);
  consume_hash1(lc, 15, ua, ub, gh, res + 30);

  float4* o4 = (float4*)(out + (size_t)i * 32);
#pragma unroll
  for (int j = 0; j < 8; ++j)
    o4[j] = make_float4(res[4 * j], res[4 * j + 1], res[4 * j + 2], res[4 * j + 3]);
}

// ---- fallback: monolithic fp32 (guards failed) ----
__global__ __launch_bounds__(256) void k_fallback(
    const float* __restrict__ pts, const float2* __restrict__ txy,
    const float2* __restrict__ txz, const float2* __restrict__ tyz,
    float* __restrict__ out, LvlC lc, int n)
{
  int i = blockIdx.x * 256 + threadIdx.x;
  if (i >= n) return;
  float u0 = (pts[3 * i + 0] + 1.f) * .5f;
  float u1 = (pts[3 * i + 1] + 1.f) * .5f;
  float u2 = (pts[3 * i + 2] + 1.f) * .5f;
  const float ua[3] = {u0, u0, u1}, ub[3] = {u1, u2, u2};
  const float2* tabs[3] = {txy, txz, tyz};
  float acc[32];
#pragma unroll
  for (int j = 0; j < 32; ++j) acc[j] = 0.f;
#pragma unroll
  for (int l = 0; l < NLEV; ++l) {
    const float sc = lc.scale[l];
    const unsigned o = lc.offset[l], s = lc.stride[l];
#pragma unroll
    for (int p = 0; p < 3; ++p) {
      const float2* t = tabs[p];
      float px = ua[p] * sc + .5f, py = ub[p] * sc + .5f;
      float fx = floorf(px), fy = floorf(py);
      float rx = px - fx, ry = py - fy;
      unsigned x0 = (unsigned)fx, y0 = (unsigned)fy;
      float w00 = (1.f - rx) * (1.f - ry), w10 = rx * (1.f - ry);
      float w01 = (1.f - rx) * ry,          w11 = rx * ry;
      float2 f00, f10, f01, f11;
      if (l >= HASH_START) {
        unsigned hy0 = y0 * HASH_PRIME, hy1 = hy0 + HASH_PRIME;
        f00 = t[o + ((x0 ^ hy0) & HMASK)];
        f10 = t[o + (((x0 + 1u) ^ hy0) & HMASK)];
        f01 = t[o + ((x0 ^ hy1) & HMASK)];
        f11 = t[o + (((x0 + 1u) ^ hy1) & HMASK)];
      } else {
        unsigned i00 = x0 + y0 * s;
        float4 r0 = *reinterpret_cast<const float4*>(t + o + i00);
        float4 r1 = *reinterpret_cast<const float4*>(t + o + i00 + s);
        f00 = make_float2(r0.x, r0.y); f10 = make_float2(r0.z, r0.w);
        f01 = make_float2(r1.x, r1.y); f11 = make_float2(r1.z, r1.w);
      }
      acc[2 * l + 0] += w00 * f00.x + w10 * f10.x + w01 * f01.x + w11 * f11.x;
      acc[2 * l + 1] += w00 * f00.y + w10 * f10.y + w01 * f01.y + w11 * f11.y;
    }
  }
  float4* o4 = (float4*)(out + (size_t)i * 32);
#pragma unroll
  for (int j = 0; j < 8; ++j)
    o4[j] = make_float4(acc[4 * j], acc[4 * j + 1], acc[4 * j + 2], acc[4 * j + 3]);
}

static unsigned compute_levels(LvlC* lc)
{
  // Mirrors Python _level_constants() with identical double-precision ops.
  const double pls = std::pow(2.0, std::log2(2048.0 / 16.0) / 15.0);
  unsigned long long off = 0;
  for (int l = 0; l < NLEV; ++l) {
    double s = 16.0 * std::pow(pls, (double)l) - 1.0;
    lc->scale[l] = (float)s;
    long long r = (long long)std::ceil(s) + 1;
    long long dense = (r + 1) * (r + 1);
    long long sz = dense < (1LL << 19) ? dense : (1LL << 19);
    sz = ((sz + 7) / 8) * 8;
    lc->stride[l] = (unsigned)(r + 1);
    lc->offset[l] = (unsigned)off;
    off += (unsigned long long)sz;
  }
  return (unsigned)off;
}

extern "C" void kernel_launch(void* const* d_in, const int* in_sizes, int n_in,
                              void* d_out, int out_size, void* d_ws, size_t ws_size,
                              hipStream_t stream) {
  const float*  pts = (const float*)d_in[0];
  const float2* txy = (const float2*)d_in[1];
  const float2* txz = (const float2*)d_in[2];
  const float2* tyz = (const float2*)d_in[3];
  float* out = (float*)d_out;
  int n = in_sizes[0] / 3;  // 1048576 points

  LvlC lc;
  unsigned total = compute_levels(&lc);

  size_t need = (size_t)3 * total * 4;

  bool ok = (n % 512 == 0) && (lc.offset[6] == LDS_WORDS) && (ws_size >= need);
  for (int l = HASH_START; l < NLEV; ++l) {
    unsigned sz = ((l + 1 < NLEV) ? lc.offset[l + 1] : total) - lc.offset[l];
    ok = ok && (sz == (1u << 19));
  }

  int block = 256;
  int grid = (n + block - 1) / block;
  if (!ok) {
    k_fallback<<<grid, block, 0, stream>>>(pts, txy, txz, tyz, out, lc, n);
    return;
  }

  unsigned* tab16 = (unsigned*)d_ws;
  k_convert<<<2048, 256, 0, stream>>>(txy, txz, tyz, tab16, total);
  k_final<<<n / 512, 512, 0, stream>>>(pts, tab16, out, lc, total, n);
}